// Round 14
// baseline (184.273 us; speedup 1.0000x reference)
//
#include <hip/hip_runtime.h>

#define DD 768
#define NCH 96
#define TPB 512        // 8 waves per block
#define ROWS_PB 512    // rows per block
#define KS 32          // rows per K-step
#define NSTEP (ROWS_PB / KS)   // 16
#define RST 18         // u32 row stride of LDS tile (16 cells + 2 pad, keeps b64 aligned)
#define FTH 768

typedef unsigned int u32;
typedef float f32x4 __attribute__((ext_vector_type(4)));
typedef short bf16x8 __attribute__((ext_vector_type(8)));
union U8 { u32 u[4]; bf16x8 v; };

#define BT_WORDS (DD * RST)   // 13824
#define LDS_BYTES ((BT_WORDS + 32 + NCH + NCH) * 4)   // 56192 B

__device__ __forceinline__ float wave_reduce_sum(float v) {
#pragma unroll
  for (int m = 32; m >= 1; m >>= 1) v += __shfl_xor(v, m, 64);
  return v;
}
__device__ __forceinline__ u32 bf2(float a, float b) {
  u32 ua = __float_as_uint(a); ua += 0x7fffu + ((ua >> 16) & 1u);
  u32 ub = __float_as_uint(b); ub += 0x7fffu + ((ub >> 16) & 1u);
  return (ua >> 16) | (ub & 0xffff0000u);
}
__device__ __forceinline__ float bflo(u32 u) { return __uint_as_float(u << 16); }
__device__ __forceinline__ float bfhi(u32 u) { return __uint_as_float(u & 0xffff0000u); }
__device__ __forceinline__ float fc(const float4& v, int j) {
  switch (j) { case 0: return v.x; case 1: return v.y; case 2: return v.z; default: return v.w; }
}

// ---------- main: sequential stream; one-hot MFMA scatter into AGPRs ----------
__global__ void __launch_bounds__(TPB) k_main(
    const float* __restrict__ x, const int* __restrict__ tgt, int n,
    u32* __restrict__ P16, float* __restrict__ Pm, float* __restrict__ Pc,
    float* __restrict__ gS, float* __restrict__ gpos, int* __restrict__ ctr) {
  extern __shared__ u32 lds[];
  u32* Bt = lds;                      // [768][18] u32 (bf16 k-pairs, slot-swizzled)
  u32* labC = lds + BT_WORDS;         // [32]
  float* mcF = (float*)(labC + 32);   // [96]
  float* ctF = mcF + NCH;             // [96]

  int tid = threadIdx.x, w = tid >> 6, l = tid & 63, blk = blockIdx.x;
  int g = l >> 4, m16 = l & 15;

  for (int i = tid; i < 2 * NCH; i += TPB) mcF[i] = 0.f;
  if (blk == 0) {  // zero finish-phase accumulators (consumed next dispatch)
    for (int i = tid; i < DD; i += TPB) gS[i] = 0.f;
    if (tid == 0) { gpos[0] = 0.f; ctr[0] = 0; }
  }

  f32x4 acc[6][6];
#pragma unroll
  for (int a = 0; a < 6; ++a)
#pragma unroll
    for (int b = 0; b < 6; ++b) acc[a][b] = (f32x4){0.f, 0.f, 0.f, 0.f};

  size_t base = (size_t)blk * ROWS_PB;

  // prologue: load step-0 rows (wave rows 4w..4w+3, fully coalesced float4)
  float4 cur[4][3];
#pragma unroll
  for (int rr = 0; rr < 4; ++rr) {
    size_t R = base + 4 * w + rr; if (R >= (size_t)n) R = (size_t)(n - 1);
    const float4* rp = (const float4*)(x + R * DD);
    cur[rr][0] = rp[l]; cur[rr][1] = rp[64 + l]; cur[rr][2] = rp[128 + l];
  }
  __syncthreads();   // mcF/ctF zero visible

  for (int t = 0; t < NSTEP; ++t) {
    size_t myrow = base + (size_t)t * KS + 4 * w;
    // ---- stats on my 4 rows (batched butterfly) ----
    float sv[4], qv[4];
#pragma unroll
    for (int rr = 0; rr < 4; ++rr) {
      float4 A = cur[rr][0], B = cur[rr][1], C = cur[rr][2];
      sv[rr] = (A.x + A.y + A.z + A.w) + (B.x + B.y + B.z + B.w) + (C.x + C.y + C.z + C.w);
      qv[rr] = A.x*A.x + A.y*A.y + A.z*A.z + A.w*A.w
             + B.x*B.x + B.y*B.y + B.z*B.z + B.w*B.w
             + C.x*C.x + C.y*C.y + C.z*C.z + C.w*C.w;
    }
#pragma unroll
    for (int mm = 32; mm >= 1; mm >>= 1) {
#pragma unroll
      for (int rr = 0; rr < 4; ++rr) {
        sv[rr] += __shfl_xor(sv[rr], mm, 64);
        qv[rr] += __shfl_xor(qv[rr], mm, 64);
      }
    }
    float rs[4], mus[4];
#pragma unroll
    for (int rr = 0; rr < 4; ++rr) {
      float mu = sv[rr] * (1.f / DD);
      float var = qv[rr] * (1.f / DD) - mu * mu;
      rs[rr] = ((myrow + rr) < (size_t)n) ? rsqrtf(var + 1e-5f) : 0.f;
      mus[rr] = mu;
    }
    // ---- pack rstd-scaled bf16 pairs into LDS (k-transposed, slot-swizzled) ----
#pragma unroll
    for (int i = 0; i < 3; ++i) {
#pragma unroll
      for (int dd = 0; dd < 4; ++dd) {
        int d = 256 * i + 4 * l + dd;
        u32 lo = bf2(rs[0] * fc(cur[0][i], dd), rs[1] * fc(cur[1][i], dd));
        u32 hi = bf2(rs[2] * fc(cur[2][i], dd), rs[3] * fc(cur[3][i], dd));
        int slot = w ^ (((d >> 2) ^ (d >> 5)) & 7);
        *(uint2*)&Bt[d * RST + 2 * slot] = make_uint2(lo, hi);
      }
    }
    // ---- labels + per-label scalar sums (4 rows per wave) ----
    if (l < 4) {
      size_t R = myrow + l;
      bool valid = R < (size_t)n;
      int lab = valid ? tgt[R] : 0;
      labC[4 * w + l] = (u32)lab;
      float myrs = (l == 0) ? rs[0] : (l == 1) ? rs[1] : (l == 2) ? rs[2] : rs[3];
      float mymu = (l == 0) ? mus[0] : (l == 1) ? mus[1] : (l == 2) ? mus[2] : mus[3];
      if (valid) {
        atomicAdd(&mcF[lab], myrs * mymu);
        atomicAdd(&ctF[lab], 1.f);
      }
    }
    __syncthreads();

    // ---- prefetch next K-step's rows (in flight across the MFMA phase) ----
    if (t + 1 < NSTEP) {
      size_t r0 = base + (size_t)(t + 1) * KS + 4 * w;
#pragma unroll
      for (int rr = 0; rr < 4; ++rr) {
        size_t R = r0 + rr; if (R >= (size_t)n) R = (size_t)(n - 1);
        const float4* rp = (const float4*)(x + R * DD);
        cur[rr][0] = rp[l]; cur[rr][1] = rp[64 + l]; cur[rr][2] = rp[128 + l];
      }
    }

    // ---- MFMA phase: A = one-hot labels (exact), B = staged tile ----
    uint4 labs_lo = *(const uint4*)&labC[4 * g];
    uint4 labs_hi = *(const uint4*)&labC[16 + 4 * g];
    U8 af[6];
#pragma unroll
    for (int RT = 0; RT < 6; ++RT) {
      int tl = 16 * RT + m16;
      af[RT].u[0] = (((int)labs_lo.x == tl) ? 0x3F80u : 0u) | (((int)labs_lo.y == tl) ? 0x3F800000u : 0u);
      af[RT].u[1] = (((int)labs_lo.z == tl) ? 0x3F80u : 0u) | (((int)labs_lo.w == tl) ? 0x3F800000u : 0u);
      af[RT].u[2] = (((int)labs_hi.x == tl) ? 0x3F80u : 0u) | (((int)labs_hi.y == tl) ? 0x3F800000u : 0u);
      af[RT].u[3] = (((int)labs_hi.z == tl) ? 0x3F80u : 0u) | (((int)labs_hi.w == tl) ? 0x3F800000u : 0u);
    }
#pragma unroll
    for (int CT = 0; CT < 6; ++CT) {
      int d = 96 * w + 16 * CT + m16;
      int ph = ((d >> 2) ^ (d >> 5)) & 7;
      uint2 blo = *(const uint2*)&Bt[d * RST + 2 * (g ^ ph)];
      uint2 bhi = *(const uint2*)&Bt[d * RST + 2 * ((4 + g) ^ ph)];
      U8 bf_;
      bf_.u[0] = blo.x; bf_.u[1] = blo.y; bf_.u[2] = bhi.x; bf_.u[3] = bhi.y;
#pragma unroll
      for (int RT = 0; RT < 6; ++RT)
        acc[RT][CT] = __builtin_amdgcn_mfma_f32_16x16x32_bf16(af[RT].v, bf_.v, acc[RT][CT], 0, 0, 0);
    }
    __syncthreads();
  }

  // ---- epilogue: bf16 partials P16[blk][96][384] ----
  int nblk = gridDim.x;
#pragma unroll
  for (int RT = 0; RT < 6; ++RT)
#pragma unroll
    for (int CT = 0; CT < 6; ++CT)
#pragma unroll
      for (int r = 0; r < 4; ++r) {
        float v = acc[RT][CT][r];
        float vx = __shfl_xor(v, 1, 64);
        if (!(l & 1)) {
          u32 pk = bf2(v, vx);
          int c = 16 * RT + 4 * g + r;                 // C row = (lane>>4)*4 + reg  [m89]
          int wordi = 48 * w + 8 * CT + (m16 >> 1);    // C col = lane&15            [m89]
          P16[((size_t)blk * NCH + c) * 384 + wordi] = pk;
        }
      }
  if (tid < NCH) {
    Pm[tid * nblk + blk] = mcF[tid];
    Pc[tid * nblk + blk] = ctF[tid];
  }
}

// ---------- finish: 96 blocks x 768 threads; partial reduce + tail math ----------
__global__ void __launch_bounds__(FTH) k_finish(
    const float* __restrict__ dic, const float* __restrict__ wln,
    const float* __restrict__ bln, const u32* __restrict__ P16,
    const float* __restrict__ Pm, const float* __restrict__ Pc, int nblk,
    float* __restrict__ gS, float* __restrict__ gpos, int* __restrict__ counter,
    float* __restrict__ out) {
  __shared__ float ps[2][384][2];
  __shared__ float mcsh, ncsh;
  __shared__ float red[12][3];
  __shared__ float fin[2];
  __shared__ int dsh;
  int c = blockIdx.x, tid = threadIdx.x, lane = tid & 63, wid = tid >> 6;
  if (tid == 0) { mcsh = 0.f; ncsh = 0.f; }
  __syncthreads();

  int h = tid / 384, word = tid % 384;
  float lo = 0.f, hi = 0.f;
  const u32* base = P16 + (size_t)c * 384;
  int b0 = h * (nblk / 2), b1 = b0 + nblk / 2;
  for (int b = b0; b < b1; ++b) {
    u32 u = base[(size_t)b * NCH * 384 + word];
    lo += bflo(u); hi += bfhi(u);
  }
  ps[h][word][0] = lo; ps[h][word][1] = hi;
  float mpart = (tid < nblk) ? Pm[c * nblk + tid] : 0.f;
  float npart = (tid < nblk) ? Pc[c * nblk + tid] : 0.f;
  mpart = wave_reduce_sum(mpart);
  npart = wave_reduce_sum(npart);
  if (lane == 0) { atomicAdd(&mcsh, mpart); atomicAdd(&ncsh, npart); }
  __syncthreads();

  int d = tid;                 // 0..767
  int wd = d >> 1, par = d & 1;
  float S1 = ps[0][wd][par] + ps[1][wd][par];
  float mcv = mcsh, nc = ncsh;
  float gg = dic[c * DD + d] + wln[d] * (S1 - mcv) + nc * bln[d];
  float inv = 1.f / (nc + 1.f);
  float u = dic[c * DD + d] + 0.1f * gg * inv;

  float pacc = wave_reduce_sum(gg * gg);
  float usum = wave_reduce_sum(u);
  float usq  = wave_reduce_sum(u * u);
  if (lane == 0) { red[wid][0] = pacc; red[wid][1] = usum; red[wid][2] = usq; }
  __syncthreads();
  if (tid == 0) {
    float tp = 0.f, ts = 0.f, tq = 0.f;
    for (int i = 0; i < 12; ++i) { tp += red[i][0]; ts += red[i][1]; tq += red[i][2]; }
    atomicAdd(gpos, tp);
    float mu = ts * (1.f / DD);
    fin[0] = mu;
    fin[1] = rsqrtf(tq * (1.f / DD) - mu * mu + 1e-5f);
  }
  __syncthreads();
  if (c >= 1) {
    float sacc = (u - fin[0]) * fin[1] * wln[d] + bln[d];
    atomicAdd(&gS[d], sacc);
  }

  __threadfence();
  __syncthreads();
  if (tid == 0) dsh = (atomicAdd(counter, 1) == NCH - 1) ? 1 : 0;
  __syncthreads();
  if (dsh) {
    __threadfence();
    float t = gS[d];
    float nv = wave_reduce_sum(t * t);
    if (lane == 0) red[wid][0] = nv;
    __syncthreads();
    if (tid == 0) {
      float tot = 0.f;
      for (int i = 0; i < 12; ++i) tot += red[i][0];
      out[0] = (tot - gpos[0]) * (1.f / DD);
    }
  }
}

extern "C" void kernel_launch(void* const* d_in, const int* in_sizes, int n_in,
                              void* d_out, int out_size, void* d_ws, size_t ws_size,
                              hipStream_t stream) {
  (void)n_in; (void)out_size; (void)ws_size;
  const float* x   = (const float*)d_in[0];
  const float* dic = (const float*)d_in[1];
  const float* w   = (const float*)d_in[2];
  const float* b   = (const float*)d_in[3];
  const int*   tgt = (const int*)d_in[4];
  float* out = (float*)d_out;
  int N = in_sizes[4];  // tokens (B*S = 131072)

  int nblk = (N + ROWS_PB - 1) / ROWS_PB;  // 256

  char* ws = (char*)d_ws;
  float* gS   = (float*)(ws);                 // 3072 B
  float* gpos = (float*)(ws + 3072);
  int*   ctr  = (int*)(ws + 3076);
  float* Pm   = (float*)(ws + 4096);                              // 96*nblk*4
  float* Pc   = (float*)(ws + 4096 + (size_t)NCH * nblk * 4);     // 96*nblk*4
  u32*   P16  = (u32*)(ws + 4096 + 2 * (size_t)NCH * nblk * 4);   // nblk*96*384*4 = 37.7 MB

  hipFuncSetAttribute((const void*)k_main,
                      hipFuncAttributeMaxDynamicSharedMemorySize, LDS_BYTES);

  k_main<<<nblk, TPB, LDS_BYTES, stream>>>(x, tgt, N, P16, Pm, Pc, gS, gpos, ctr);
  k_finish<<<NCH, FTH, 0, stream>>>(dic, w, b, P16, Pm, Pc, nblk,
                                    gS, gpos, ctr, out);
}